// Round 6
// baseline (1914.316 us; speedup 1.0000x reference)
//
#include <hip/hip_runtime.h>
#include <stdint.h>

#define B_ 4
#define T_ 4096
#define D_ 1024
#define H_ 16
#define HD_ 64
#define C_ 64
#define N_ 64
#define BT_ (B_*T_)

typedef _Float16 f16;
typedef f16 f16x4 __attribute__((ext_vector_type(4)));
typedef f16 f16x8 __attribute__((ext_vector_type(8)));
typedef float f32x4 __attribute__((ext_vector_type(4)));

__device__ __forceinline__ float wave_sum(float v){
  #pragma unroll
  for(int off=32; off>0; off>>=1) v += __shfl_down(v, off);
  return __shfl(v, 0);
}
__device__ __forceinline__ float dot4(float4 a, float4 b){
  return a.x*b.x + a.y*b.y + a.z*b.z + a.w*b.w;
}

// ---------------------------------------------------------------------------
// K1 v2: tiled skinny GEMM (16 rows/block, 256 thr).
// ---------------------------------------------------------------------------
#define KSR 16   // rows per block
__global__ __launch_bounds__(256) void k_small(const float* __restrict__ x,
    const float* __restrict__ wg, const float* __restrict__ wb, const float* __restrict__ wa,
    const float* __restrict__ dtb, const float* __restrict__ alog,
    float* __restrict__ invn, float* __restrict__ gate, float* __restrict__ beta,
    float* __restrict__ dec){
  __shared__ float Xs [KSR][68];
  __shared__ float Wgt[H_ ][68];
  __shared__ float Wbt[H_ ][68];
  __shared__ float Wat[H_ ][68];
  int tid = threadIdx.x;
  int r = tid>>4, h = tid&15;
  int row0 = blockIdx.x*KSR;

  int sr = tid>>4, sf = (tid&15);      // x: row sr, float4 slot sf
  int wk = tid>>2, wj = tid&3;         // W: k row wk, float4 col slot wj

  float dg=0.f, db=0.f, da=0.f, ss=0.f;

  float4 px = *(const float4*)(x + (size_t)(row0+sr)*D_ + sf*4);
  float4 pg = *(const float4*)(wg + (size_t)wk*H_ + 4*wj);
  float4 pb = *(const float4*)(wb + (size_t)wk*H_ + 4*wj);
  float4 pa = *(const float4*)(wa + (size_t)wk*H_ + 4*wj);

  for(int t=0; t<16; ++t){
    __syncthreads();
    *(float4*)&Xs[sr][sf*4] = px;
    Wgt[4*wj+0][wk]=pg.x; Wgt[4*wj+1][wk]=pg.y; Wgt[4*wj+2][wk]=pg.z; Wgt[4*wj+3][wk]=pg.w;
    Wbt[4*wj+0][wk]=pb.x; Wbt[4*wj+1][wk]=pb.y; Wbt[4*wj+2][wk]=pb.z; Wbt[4*wj+3][wk]=pb.w;
    Wat[4*wj+0][wk]=pa.x; Wat[4*wj+1][wk]=pa.y; Wat[4*wj+2][wk]=pa.z; Wat[4*wj+3][wk]=pa.w;
    if(t<15){
      int k0 = (t+1)*64;
      px = *(const float4*)(x + (size_t)(row0+sr)*D_ + k0 + sf*4);
      pg = *(const float4*)(wg + (size_t)(k0+wk)*H_ + 4*wj);
      pb = *(const float4*)(wb + (size_t)(k0+wk)*H_ + 4*wj);
      pa = *(const float4*)(wa + (size_t)(k0+wk)*H_ + 4*wj);
    }
    __syncthreads();
    #pragma unroll
    for(int q=0;q<16;++q){
      float4 xv = *(const float4*)&Xs[r][4*q];
      float4 g4 = *(const float4*)&Wgt[h][4*q];
      float4 b4 = *(const float4*)&Wbt[h][4*q];
      float4 a4 = *(const float4*)&Wat[h][4*q];
      dg += dot4(xv,g4);
      db += dot4(xv,b4);
      da += dot4(xv,a4);
      if(t==h) ss += dot4(xv,xv);
    }
  }

  int o = row0*H_ + tid;
  invn[o] = 1.f/fmaxf(sqrtf(ss),1e-12f);
  gate[o] = 1.f/(1.f+expf(-dg));
  beta[o] = 1.f/(1.f+expf(-db));
  float z = da + dtb[h];
  float sp = (z>20.f)? z : log1pf(expf(z));
  dec[o] = -expf(alog[h])*sp;
}

// ---------------------------------------------------------------------------
// K_TR: wt[n][k] = (f16)w[k][n], 1024x1024. Two weights in one launch (z).
// ---------------------------------------------------------------------------
__global__ __launch_bounds__(256) void k_tr(const float* __restrict__ w0,
    const float* __restrict__ w1, f16* __restrict__ t0, f16* __restrict__ t1){
  const float* w = blockIdx.z ? w1 : w0;
  f16* wt        = blockIdx.z ? t1 : t0;
  __shared__ float T[64*68];
  int tid = threadIdx.x;
  int bj = blockIdx.x, bi = blockIdx.y;   // bi: k-tile, bj: n-tile
  #pragma unroll
  for(int j=0;j<4;++j){
    int idx = tid + 256*j;
    int r = idx>>4, q = idx&15;
    float4 u = *(const float4*)(w + (size_t)(bi*64+r)*1024 + bj*64 + 4*q);
    T[(4*q+0)*68 + r] = u.x;
    T[(4*q+1)*68 + r] = u.y;
    T[(4*q+2)*68 + r] = u.z;
    T[(4*q+3)*68 + r] = u.w;
  }
  __syncthreads();
  int cc = tid>>2, seg = tid&3;
  f16 h[16];
  #pragma unroll
  for(int u2=0;u2<4;++u2){
    float4 f = *(const float4*)&T[cc*68 + seg*16 + 4*u2];
    h[4*u2+0]=(f16)f.x; h[4*u2+1]=(f16)f.y; h[4*u2+2]=(f16)f.z; h[4*u2+3]=(f16)f.w;
  }
  size_t o = (size_t)(bj*64+cc)*1024 + bi*64 + seg*16;
  *(f16x8*)(wt + o)     = *(f16x8*)&h[0];
  *(f16x8*)(wt + o + 8) = *(f16x8*)&h[8];
}

// ---------------------------------------------------------------------------
// K_GEMM16: C(f32) = A(f32, cast f16) @ BT^T (+resid). MFMA 16x16x32_f16.
//   1D grid 1024, XCD-aware decode: within each 64-block group, bid%8 (=XCD)
//   fixes the m-tile, so each XCD fetches one 512KB A-panel per group and
//   reuses it across all 8 n-tiles from its L2 (A fetched ~1x, not 8x).
// ---------------------------------------------------------------------------
__global__ __launch_bounds__(256) void k_gemm16(const float* __restrict__ A,
    const f16* __restrict__ BT, const float* __restrict__ resid,
    float* __restrict__ C, int addres){
  __shared__ f16 Al[128*72];
  __shared__ f16 Bl[128*72];
  int tid = threadIdx.x;
  int bid = blockIdx.x;
  int g = bid>>6, t = bid&63;
  int m0 = (g*8 + (t&7))*128, n0 = (t>>3)*128;
  int w = tid>>6, l = tid&63;
  int wm = (w>>1)*64, wn = (w&1)*64;
  int lr = l&15, lq = l>>4;
  f32x4 acc[4][4] = {};
  for(int k0=0; k0<1024; k0+=64){
    __syncthreads();   // previous compute done reading LDS
    #pragma unroll
    for(int j=0;j<8;++j){
      int idx = tid + 256*j;
      int m = idx>>4, q = idx&15;
      float4 u = *(const float4*)(A + (size_t)(m0+m)*1024 + k0 + 4*q);
      f16x4 hv; hv[0]=(f16)u.x; hv[1]=(f16)u.y; hv[2]=(f16)u.z; hv[3]=(f16)u.w;
      *(f16x4*)&Al[m*72 + 4*q] = hv;
    }
    #pragma unroll
    for(int j=0;j<4;++j){
      int idx = tid + 256*j;
      int n = idx>>3, o8 = idx&7;
      f16x8 hv = *(const f16x8*)(BT + (size_t)(n0+n)*1024 + k0 + 8*o8);
      *(f16x8*)&Bl[n*72 + 8*o8] = hv;
    }
    __syncthreads();
    #pragma unroll
    for(int kb=0; kb<64; kb+=32){
      f16x8 a[4], b[4];
      #pragma unroll
      for(int i=0;i<4;++i){
        a[i] = *(const f16x8*)&Al[(wm + i*16 + lr)*72 + kb + 8*lq];
        b[i] = *(const f16x8*)&Bl[(wn + i*16 + lr)*72 + kb + 8*lq];
      }
      #pragma unroll
      for(int mi=0;mi<4;++mi)
        #pragma unroll
        for(int ni=0;ni<4;++ni)
          acc[mi][ni] = __builtin_amdgcn_mfma_f32_16x16x32_f16(a[mi], b[ni], acc[mi][ni], 0,0,0);
    }
  }
  #pragma unroll
  for(int mi=0;mi<4;++mi){
    #pragma unroll
    for(int r=0;r<4;++r){
      int m = m0 + wm + mi*16 + lq*4 + r;
      #pragma unroll
      for(int ni=0;ni<4;++ni){
        int n = n0 + wn + ni*16 + lr;
        size_t o = (size_t)m*1024 + n;
        float v = acc[mi][ni][r];
        if(addres) v += resid[o];
        C[o] = v;
      }
    }
  }
}

// ---------------------------------------------------------------------------
// K3: per-chunk: cum, KK, forward substitution -> v_corr (in-place in vbuf),
//     wk_cd -> wkop. Also zeroes this chunk's psum/cnt team-sync slot.
// ---------------------------------------------------------------------------
__global__ __launch_bounds__(256) void k_chunk(const float* __restrict__ x,
    const float* __restrict__ invn, const float* __restrict__ beta_g,
    const float* __restrict__ dec_g, float* __restrict__ cum_g,
    float* __restrict__ vbuf, float* __restrict__ wkop,
    float* __restrict__ psum, int* __restrict__ cnt){
  int bid = blockIdx.x;                  // b*H*N + h*N + n  == bh*64 + n
  int n = bid & 63; int h = (bid>>6) & 15; int b = bid>>10;
  int t0 = n*C_;
  __shared__ float sm[12608];
  float* WK = sm;            // 64*65 (padded), aliased by XV later
  float* KK = sm+4160;       // 64*64
  float* XW = sm+8256;       // 64*64
  float* BS = sm+12352;      // 64
  float* CU = sm+12416;      // 64
  float* DE = sm+12480;      // 64
  float* GS = sm+12544;      // 64
  float* XV = WK;            // 4096 over WK region (stride 64)
  int tid = threadIdx.x, w = tid>>6, l = tid&63;
  if(tid==0){ psum[bid]=0.f; cnt[bid]=0; }   // reset team-sync slot for k_scan
  // A: stage shifted normalized keys + beta + decay
  #pragma unroll
  for(int it=0; it<16; ++it){
    int idx = tid + 256*it; int c = idx>>6, dd = idx&63;
    int tw = t0+c-1;
    float wv = 0.f;
    if(tw>=0){
      size_t rr = (size_t)(b*T_+tw);
      wv = x[rr*D_ + h*64 + dd] * invn[rr*H_ + h];
    }
    WK[c*65+dd] = wv;
  }
  if(tid<64){
    size_t rr = (size_t)(b*T_+t0+tid);
    BS[tid] = beta_g[rr*H_+h];
    GS[tid] = dec_g[rr*H_+h];
  }
  __syncthreads();
  // B: inclusive cumsum of decay (wave 0)
  if(w==0){
    float xg = GS[l];
    #pragma unroll
    for(int off=1; off<64; off<<=1){
      float y = __shfl_up(xg, off);
      if(l>=off) xg += y;
    }
    CU[l]=xg; DE[l]=expf(xg);
    cum_g[(size_t)bid*64 + l] = xg;
  }
  __syncthreads();
  // C: KK[i][j] = beta_i * (wk_i . wk_j) * L[i][j], strict lower
  float wkj[64];
  #pragma unroll
  for(int dd=0; dd<64; ++dd) wkj[dd] = WK[l*65+dd];
  #pragma unroll 1
  for(int it=0; it<16; ++it){
    int i = w + 4*it;
    float aw=0.f;
    #pragma unroll
    for(int dd=0; dd<64; ++dd) aw += WK[i*65+dd]*wkj[dd];
    KK[i*64+l] = (l<i) ? (BS[i]*aw*expf(CU[i]-CU[l])) : 0.f;
  }
  __syncthreads();
  // D: capture rhs into regs, then write XV (over WK), XW
  float rv[16], rw[16];
  #pragma unroll
  for(int it=0; it<16; ++it){
    int i = w + 4*it;
    rw[it] = WK[i*65+l]*BS[i]*DE[i];
    rv[it] = vbuf[(size_t)(b*T_+t0+i)*D_ + h*64 + l]*BS[i];
  }
  __syncthreads();
  #pragma unroll
  for(int it=0; it<16; ++it){
    int i = w + 4*it;
    XV[i*64+l] = rv[it];
    XW[i*64+l] = rw[it];
  }
  __syncthreads();
  // E: forward substitution (I + strict_lower(KK)) X = rhs (waves 0,1)
  if(w<2){
    float* Xc = (w==0) ? XV : XW;
    for(int i=1;i<64;++i){
      float acc = Xc[i*64+l];
      for(int k=0;k<i;++k) acc -= KK[i*64+k]*Xc[k*64+l];
      Xc[i*64+l] = acc;
    }
  }
  __syncthreads();
  // F: write v_corr (in place), wk_cd
  #pragma unroll
  for(int it=0; it<16; ++it){
    int i = w + 4*it;
    vbuf[(size_t)(b*T_+t0+i)*D_ + h*64 + l] = XV[i*64+l];
    wkop[(size_t)bid*4096 + i*64 + l]       = XW[i*64+l];
  }
}

// ---------------------------------------------------------------------------
// K4 v5: column-split team scan, 4-col register tiling. Stage/prefetch by all
//   16 waves; gemv + S-update run on 4 waves (256 thr), thread = (row, 4 cols)
//   -> 2.7x less LDS read traffic in gemv (6 b128 / 32 FMA vs 3/8), the
//   measured bottleneck (LDS-BW). FP order per column unchanged. Team sync
//   (bounded spin, lazy scale) identical to verified v4b.
// ---------------------------------------------------------------------------
__global__ __launch_bounds__(1024, 4) void k_scan(const float* __restrict__ x,
    const float* __restrict__ invn_g, const float* __restrict__ cum_g,
    float* __restrict__ vbuf, float* __restrict__ wkop,
    float* __restrict__ psum, int* __restrict__ cnt){
  int bh = blockIdx.x & 63, cg4 = blockIdx.x >> 6;
  int b = bh>>4, h = bh&15, col0 = cg4*16;
  __shared__ float sm[15448];
  float* WCD = sm;           // [64][68] wkcd rows
  float* RK  = sm+4352;      // [64][68] rk rows (scaled by invn)
  float* WKT = sm+8704;      // [64][68] WKT[d][c] = wk[c][d] (col 0 = PREV)
  float* VNS = sm+13056;     // [16][68] VNS[col][c] = v_new*DW, transposed
  float* ST  = sm+14144;     // [16][68] ST[col][d] = S (UNSCALED U), transposed
  float* DW  = sm+15232;     // 64: exp(last-cum)
  float* DEc = sm+15296;     // 64: exp(cum)
  float* PREV= sm+15360;     // 64: prev chunk's last rk row
  float* P   = sm+15424;     // 4 used
  float* NRM = sm+15440;     // 1
  int tid = threadIdx.x, w = tid>>6, l = tid&63;
  int cs = tid>>4, q4 = tid&15;    // stage mapping: row / float4-slot
  int gc = tid>>2, cq = tid&3;     // compute mapping (tid<256): row(d) / col-quad

  for(int i=tid;i<1088;i+=1024) ST[i]=0.f;
  if(tid<64) PREV[tid]=0.f;

  // prologue prefetch chunk 0
  float4 pW, pR, pV; float pIv, pC=0.f, pLast=0.f;
  {
    size_t base0 = (size_t)bh*N_*4096;
    pW = *(const float4*)(wkop + base0 + (size_t)tid*4);
    pR = *(const float4*)(x + (size_t)(b*T_+cs)*D_ + h*64 + 4*q4);
    pIv = invn_g[(size_t)(b*T_+cs)*H_ + h];
    if(tid<256)
      pV = *(const float4*)(vbuf + (size_t)(b*T_+gc)*D_ + h*64 + col0 + 4*cq);
    if(tid<64){
      pC    = cum_g[(size_t)bh*N_*64 + tid];
      pLast = cum_g[(size_t)bh*N_*64 + 63];
    }
  }
  __syncthreads();

  float scale = 1.f;
  for(int n=0;n<N_;++n){
    int t0 = n*C_;
    size_t base = ((size_t)bh*N_+n)*4096;
    // ---- stage (all 16 waves) ----
    *(float4*)&WCD[cs*68+4*q4] = pW;
    float4 rv4;
    rv4.x=pR.x*pIv; rv4.y=pR.y*pIv; rv4.z=pR.z*pIv; rv4.w=pR.w*pIv;
    *(float4*)&RK[cs*68+4*q4] = rv4;
    if(cs<63){
      WKT[(4*q4+0)*68 + cs+1]=rv4.x;
      WKT[(4*q4+1)*68 + cs+1]=rv4.y;
      WKT[(4*q4+2)*68 + cs+1]=rv4.z;
      WKT[(4*q4+3)*68 + cs+1]=rv4.w;
    }
    if(tid<64){
      WKT[tid*68+0] = PREV[tid];
      DW[tid]  = expf(pLast-pC);
      DEc[tid] = expf(pC);
    }
    // ---- bounded spin for previous chunk's team norm ----
    if(n>0 && tid==0){
      int slot = bh*N_ + n-1;
      int guard = 0;
      while(__hip_atomic_load(&cnt[slot], __ATOMIC_ACQUIRE, __HIP_MEMORY_SCOPE_AGENT) < 4
            && guard < (1<<20)){
        __builtin_amdgcn_s_sleep(8);
        ++guard;
      }
      NRM[0] = __hip_atomic_load(&psum[slot], __ATOMIC_RELAXED, __HIP_MEMORY_SCOPE_AGENT);
    }
    __syncthreads();   // B1
    if(n>0){
      float nr = sqrtf(NRM[0]);
      scale = fminf(nr,100.f)/fmaxf(nr,1e-6f);
    }
    float4 vcur;
    if(tid<256) vcur = pV;
    // ---- prefetch chunk n+1 (drained by B3 before the release-add) ----
    if(n+1<N_){
      int t1 = t0 + C_;
      size_t base1 = base + 4096;
      pW = *(const float4*)(wkop + base1 + (size_t)tid*4);
      pR = *(const float4*)(x + (size_t)(b*T_+t1+cs)*D_ + h*64 + 4*q4);
      pIv = invn_g[(size_t)(b*T_+t1+cs)*H_ + h];
      if(tid<256)
        pV = *(const float4*)(vbuf + (size_t)(b*T_+t1+gc)*D_ + h*64 + col0 + 4*cq);
      if(tid<64){
        pC    = cum_g[((size_t)bh*N_+n+1)*64 + tid];
        pLast = cum_g[((size_t)bh*N_+n+1)*64 + 63];
      }
    }
    // ---- gemv (waves 0-3): thread (gc, cols 4cq..4cq+3) ----
    if(tid<256){
      float4 da = {0.f,0.f,0.f,0.f}, dr = {0.f,0.f,0.f,0.f};
      #pragma unroll
      for(int q=0;q<16;++q){
        float4 wv = *(const float4*)&WCD[gc*68+4*q];
        float4 rr = *(const float4*)&RK [gc*68+4*q];
        float4 s0 = *(const float4*)&ST [(4*cq+0)*68+4*q];
        float4 s1 = *(const float4*)&ST [(4*cq+1)*68+4*q];
        float4 s2 = *(const float4*)&ST [(4*cq+2)*68+4*q];
        float4 s3 = *(const float4*)&ST [(4*cq+3)*68+4*q];
        da.x += dot4(wv,s0); da.y += dot4(wv,s1);
        da.z += dot4(wv,s2); da.w += dot4(wv,s3);
        dr.x += dot4(rr,s0); dr.y += dot4(rr,s1);
        dr.z += dot4(rr,s2); dr.w += dot4(rr,s3);
      }
      float dwc = DW[gc], dsc = DEc[gc]*scale;
      float4 vn;
      vn.x = vcur.x - scale*da.x; vn.y = vcur.y - scale*da.y;
      vn.z = vcur.z - scale*da.z; vn.w = vcur.w - scale*da.w;
      *(float4*)(vbuf + (size_t)(b*T_+t0+gc)*D_ + h*64 + col0 + 4*cq) = vn;
      float4 op;
      op.x = dsc*dr.x; op.y = dsc*dr.y; op.z = dsc*dr.z; op.w = dsc*dr.w;
      *(float4*)(wkop + base + gc*64 + col0 + 4*cq) = op;
      VNS[(4*cq+0)*68+gc] = vn.x*dwc;
      VNS[(4*cq+1)*68+gc] = vn.y*dwc;
      VNS[(4*cq+2)*68+gc] = vn.z*dwc;
      VNS[(4*cq+3)*68+gc] = vn.w*dwc;
    }
    __syncthreads();   // B2
    if(tid<64) PREV[tid] = RK[63*68+tid];
    // ---- S update (waves 0-3): thread (d=gc, cols 4cq..4cq+3) ----
    float sn0=0.f, sn1=0.f, sn2=0.f, sn3=0.f;
    if(tid<256){
      float el = DEc[63]*scale;
      sn0 = el*ST[(4*cq+0)*68+gc];
      sn1 = el*ST[(4*cq+1)*68+gc];
      sn2 = el*ST[(4*cq+2)*68+gc];
      sn3 = el*ST[(4*cq+3)*68+gc];
      #pragma unroll
      for(int q=0;q<16;++q){
        float4 wt = *(const float4*)&WKT[gc*68+4*q];
        float4 v0 = *(const float4*)&VNS[(4*cq+0)*68+4*q];
        float4 v1 = *(const float4*)&VNS[(4*cq+1)*68+4*q];
        float4 v2 = *(const float4*)&VNS[(4*cq+2)*68+4*q];
        float4 v3 = *(const float4*)&VNS[(4*cq+3)*68+4*q];
        sn0 += dot4(wt,v0); sn1 += dot4(wt,v1);
        sn2 += dot4(wt,v2); sn3 += dot4(wt,v3);
      }
      float p = sn0*sn0 + sn1*sn1 + sn2*sn2 + sn3*sn3;
      p = wave_sum(p);
      if(l==0) P[w]=p;
    }
    __syncthreads();   // B3 (drains vmcnt: prefetches landed before release)
    if(tid==0 && n+1<N_){
      float pl = P[0]+P[1]+P[2]+P[3];
      int slot = bh*N_ + n;
      __hip_atomic_fetch_add(&psum[slot], pl, __ATOMIC_RELAXED, __HIP_MEMORY_SCOPE_AGENT);
      __hip_atomic_fetch_add(&cnt[slot], 1, __ATOMIC_RELEASE, __HIP_MEMORY_SCOPE_AGENT);
    }
    if(tid<256){   // unscaled U; next chunk applies scale lazily
      ST[(4*cq+0)*68+gc] = sn0;
      ST[(4*cq+1)*68+gc] = sn1;
      ST[(4*cq+2)*68+gc] = sn2;
      ST[(4*cq+3)*68+gc] = sn3;
    }
  }
}

// ---------------------------------------------------------------------------
// K5: o = gate*(opart + intra @ v_new); intra recomputed from rk/wk; o in-place
// ---------------------------------------------------------------------------
__global__ __launch_bounds__(256) void k_o(const float* __restrict__ x,
    const float* __restrict__ invn, const float* __restrict__ cum_g,
    const float* __restrict__ wkop, const float* __restrict__ gate_g,
    float* __restrict__ vbuf){
  int bid = blockIdx.x; int n = bid&63, h=(bid>>6)&15, b=bid>>10;
  int t0 = n*C_;
  __shared__ float sm[8256];
  float* RK = sm;        // 64x64 rk chunk, later INT (intra)
  float* VN = sm+4096;   // 64x64 v_new chunk
  float* CU = sm+8192;   // 64
  float* INT = RK;
  int tid=threadIdx.x, w=tid>>6, l=tid&63;
  if(tid<64) CU[tid] = cum_g[(size_t)bid*64 + tid];
  #pragma unroll 1
  for(int it=0;it<16;++it){
    int idx = tid+256*it; int c=idx>>6, dd=idx&63;
    size_t rr = (size_t)(b*T_+t0+c);
    RK[c*64+dd] = x[rr*D_ + h*64 + dd] * invn[rr*H_ + h];
    VN[idx]     = vbuf[rr*D_ + h*64 + dd];
  }
  __syncthreads();
  float wkj[64];
  {
    int tw = t0+l-1;
    if(tw>=0){
      size_t r2 = (size_t)(b*T_+tw);
      float iv = invn[r2*H_ + h];
      #pragma unroll
      for(int d4=0; d4<16; ++d4){
        float4 u = *(const float4*)(x + r2*D_ + h*64 + 4*d4);
        wkj[4*d4+0]=u.x*iv; wkj[4*d4+1]=u.y*iv;
        wkj[4*d4+2]=u.z*iv; wkj[4*d4+3]=u.w*iv;
      }
    } else {
      #pragma unroll
      for(int dd=0;dd<64;++dd) wkj[dd]=0.f;
    }
  }
  #pragma unroll 1
  for(int it=0;it<16;++it){
    int i = w + 4*it;
    float ar = 0.f;
    #pragma unroll
    for(int d4=0; d4<16; ++d4){
      float4 r4 = *(const float4*)&RK[i*64 + 4*d4];
      ar += r4.x*wkj[4*d4] + r4.y*wkj[4*d4+1] + r4.z*wkj[4*d4+2] + r4.w*wkj[4*d4+3];
    }
    float val = (l<=i) ? (ar*expf(CU[i]-CU[l])) : 0.f;
    INT[i*64+l] = val;
  }
  __syncthreads();
  float vn_col[64];
  #pragma unroll
  for(int k=0;k<64;++k) vn_col[k] = VN[k*64+l];
  #pragma unroll 1
  for(int it=0;it<16;++it){
    int c = w+4*it;
    float acc = 0.f;
    #pragma unroll
    for(int d4=0; d4<16; ++d4){
      float4 i4 = *(const float4*)&INT[c*64 + 4*d4];
      acc += i4.x*vn_col[4*d4] + i4.y*vn_col[4*d4+1] + i4.z*vn_col[4*d4+2] + i4.w*vn_col[4*d4+3];
    }
    size_t rr = (size_t)(b*T_+t0+c);
    float g  = gate_g[rr*H_ + h];
    float op = wkop[(size_t)bid*4096 + c*64 + l];
    vbuf[rr*D_ + h*64 + l] = (op + acc)*g;
  }
}

// ---------------------------------------------------------------------------
extern "C" void kernel_launch(void* const* d_in, const int* in_sizes, int n_in,
                              void* d_out, int out_size, void* d_ws, size_t ws_size,
                              hipStream_t stream) {
  const float* x       = (const float*)d_in[0];
  const float* w_write = (const float*)d_in[1];
  const float* w_gate  = (const float*)d_in[2];
  const float* w_out   = (const float*)d_in[3];
  const float* w_beta  = (const float*)d_in[4];
  const float* w_alpha = (const float*)d_in[5];
  const float* dt_bias = (const float*)d_in[6];
  const float* A_log   = (const float*)d_in[7];
  float* outp = (float*)d_out;

  const size_t big   = (size_t)BT_*D_;   // 16,777,216 floats
  const size_t small = (size_t)BT_*H_;   //    262,144 floats
  const size_t nslot = (size_t)B_*H_*N_; //       4096 team-sync slots
  const size_t wsz   = (size_t)D_*D_;    //  1,048,576 halves per weight
  const size_t need  = (2*big + 5*small + 2*nslot)*sizeof(float) + 2*wsz*sizeof(f16);
  if(ws_size < need) return;   // diagnostic: wrong-answer instead of fault

  float* ws   = (float*)d_ws;
  float* vbuf = ws;              // v -> v_corr -> v_new -> o
  float* wkop = vbuf + big;      // wk_cd -> opart
  float* invn = wkop + big;
  float* gate = invn + small;
  float* beta = gate + small;
  float* dec  = beta + small;
  float* cum  = dec  + small;
  float* psum = cum  + small;
  int*   cnt  = (int*)(psum + nslot);
  f16*   wtw  = (f16*)(cnt + nslot);     // w_write^T in f16 [n][k]
  f16*   wto  = wtw + wsz;               // w_out^T   in f16 [n][k]

  k_tr<<<dim3(16,16,2), dim3(256), 0, stream>>>(w_write, w_out, wtw, wto);
  k_small<<<dim3(BT_/KSR), dim3(256), 0, stream>>>(x, w_gate, w_beta, w_alpha,
      dt_bias, A_log, invn, gate, beta, dec);
  k_gemm16<<<dim3(1024), dim3(256), 0, stream>>>(x, wtw,
      (const float*)0, vbuf, 0);
  k_chunk<<<dim3(B_*H_*N_), dim3(256), 0, stream>>>(x, invn, beta, dec,
      cum, vbuf, wkop, psum, cnt);
  k_scan<<<dim3(4*B_*H_), dim3(1024), 0, stream>>>(x, invn, cum, vbuf, wkop,
      psum, cnt);
  k_o<<<dim3(B_*H_*N_), dim3(256), 0, stream>>>(x, invn, cum, wkop, gate, vbuf);
  k_gemm16<<<dim3(1024), dim3(256), 0, stream>>>(vbuf, wto, x,
      outp, 1);
}

// Round 7
// 1186.865 us; speedup vs baseline: 1.6129x; 1.6129x over previous
//
#include <hip/hip_runtime.h>
#include <stdint.h>

#define B_ 4
#define T_ 4096
#define D_ 1024
#define H_ 16
#define HD_ 64
#define C_ 64
#define N_ 64
#define BT_ (B_*T_)

typedef _Float16 f16;
typedef f16 f16x4 __attribute__((ext_vector_type(4)));
typedef f16 f16x8 __attribute__((ext_vector_type(8)));
typedef float f32x4 __attribute__((ext_vector_type(4)));

__device__ __forceinline__ float wave_sum(float v){
  #pragma unroll
  for(int off=32; off>0; off>>=1) v += __shfl_down(v, off);
  return __shfl(v, 0);
}
__device__ __forceinline__ float dot4(float4 a, float4 b){
  return a.x*b.x + a.y*b.y + a.z*b.z + a.w*b.w;
}

// ---------------------------------------------------------------------------
// K1 v2: tiled skinny GEMM (16 rows/block, 256 thr).
// ---------------------------------------------------------------------------
#define KSR 16   // rows per block
__global__ __launch_bounds__(256) void k_small(const float* __restrict__ x,
    const float* __restrict__ wg, const float* __restrict__ wb, const float* __restrict__ wa,
    const float* __restrict__ dtb, const float* __restrict__ alog,
    float* __restrict__ invn, float* __restrict__ gate, float* __restrict__ beta,
    float* __restrict__ dec){
  __shared__ float Xs [KSR][68];
  __shared__ float Wgt[H_ ][68];
  __shared__ float Wbt[H_ ][68];
  __shared__ float Wat[H_ ][68];
  int tid = threadIdx.x;
  int r = tid>>4, h = tid&15;
  int row0 = blockIdx.x*KSR;

  int sr = tid>>4, sf = (tid&15);      // x: row sr, float4 slot sf
  int wk = tid>>2, wj = tid&3;         // W: k row wk, float4 col slot wj

  float dg=0.f, db=0.f, da=0.f, ss=0.f;

  float4 px = *(const float4*)(x + (size_t)(row0+sr)*D_ + sf*4);
  float4 pg = *(const float4*)(wg + (size_t)wk*H_ + 4*wj);
  float4 pb = *(const float4*)(wb + (size_t)wk*H_ + 4*wj);
  float4 pa = *(const float4*)(wa + (size_t)wk*H_ + 4*wj);

  for(int t=0; t<16; ++t){
    __syncthreads();
    *(float4*)&Xs[sr][sf*4] = px;
    Wgt[4*wj+0][wk]=pg.x; Wgt[4*wj+1][wk]=pg.y; Wgt[4*wj+2][wk]=pg.z; Wgt[4*wj+3][wk]=pg.w;
    Wbt[4*wj+0][wk]=pb.x; Wbt[4*wj+1][wk]=pb.y; Wbt[4*wj+2][wk]=pb.z; Wbt[4*wj+3][wk]=pb.w;
    Wat[4*wj+0][wk]=pa.x; Wat[4*wj+1][wk]=pa.y; Wat[4*wj+2][wk]=pa.z; Wat[4*wj+3][wk]=pa.w;
    if(t<15){
      int k0 = (t+1)*64;
      px = *(const float4*)(x + (size_t)(row0+sr)*D_ + k0 + sf*4);
      pg = *(const float4*)(wg + (size_t)(k0+wk)*H_ + 4*wj);
      pb = *(const float4*)(wb + (size_t)(k0+wk)*H_ + 4*wj);
      pa = *(const float4*)(wa + (size_t)(k0+wk)*H_ + 4*wj);
    }
    __syncthreads();
    #pragma unroll
    for(int q=0;q<16;++q){
      float4 xv = *(const float4*)&Xs[r][4*q];
      float4 g4 = *(const float4*)&Wgt[h][4*q];
      float4 b4 = *(const float4*)&Wbt[h][4*q];
      float4 a4 = *(const float4*)&Wat[h][4*q];
      dg += dot4(xv,g4);
      db += dot4(xv,b4);
      da += dot4(xv,a4);
      if(t==h) ss += dot4(xv,xv);
    }
  }

  int o = row0*H_ + tid;
  invn[o] = 1.f/fmaxf(sqrtf(ss),1e-12f);
  gate[o] = 1.f/(1.f+expf(-dg));
  beta[o] = 1.f/(1.f+expf(-db));
  float z = da + dtb[h];
  float sp = (z>20.f)? z : log1pf(expf(z));
  dec[o] = -expf(alog[h])*sp;
}

// ---------------------------------------------------------------------------
// K_TR: wt[n][k] = (f16)w[k][n], 1024x1024. Two weights in one launch (z).
// ---------------------------------------------------------------------------
__global__ __launch_bounds__(256) void k_tr(const float* __restrict__ w0,
    const float* __restrict__ w1, f16* __restrict__ t0, f16* __restrict__ t1){
  const float* w = blockIdx.z ? w1 : w0;
  f16* wt        = blockIdx.z ? t1 : t0;
  __shared__ float T[64*68];
  int tid = threadIdx.x;
  int bj = blockIdx.x, bi = blockIdx.y;   // bi: k-tile, bj: n-tile
  #pragma unroll
  for(int j=0;j<4;++j){
    int idx = tid + 256*j;
    int r = idx>>4, q = idx&15;
    float4 u = *(const float4*)(w + (size_t)(bi*64+r)*1024 + bj*64 + 4*q);
    T[(4*q+0)*68 + r] = u.x;
    T[(4*q+1)*68 + r] = u.y;
    T[(4*q+2)*68 + r] = u.z;
    T[(4*q+3)*68 + r] = u.w;
  }
  __syncthreads();
  int cc = tid>>2, seg = tid&3;
  f16 h[16];
  #pragma unroll
  for(int u2=0;u2<4;++u2){
    float4 f = *(const float4*)&T[cc*68 + seg*16 + 4*u2];
    h[4*u2+0]=(f16)f.x; h[4*u2+1]=(f16)f.y; h[4*u2+2]=(f16)f.z; h[4*u2+3]=(f16)f.w;
  }
  size_t o = (size_t)(bj*64+cc)*1024 + bi*64 + seg*16;
  *(f16x8*)(wt + o)     = *(f16x8*)&h[0];
  *(f16x8*)(wt + o + 8) = *(f16x8*)&h[8];
}

// ---------------------------------------------------------------------------
// K_GEMM16: C(f32) = A(f32, cast f16) @ BT^T (+resid). MFMA 16x16x32_f16.
//   1D grid 1024, XCD-aware decode: within each 64-block group, bid%8 (=XCD)
//   fixes the m-tile, so each XCD fetches one 512KB A-panel per group and
//   reuses it across all 8 n-tiles from its L2 (A fetched ~1x, not 8x).
// ---------------------------------------------------------------------------
__global__ __launch_bounds__(256) void k_gemm16(const float* __restrict__ A,
    const f16* __restrict__ BT, const float* __restrict__ resid,
    float* __restrict__ C, int addres){
  __shared__ f16 Al[128*72];
  __shared__ f16 Bl[128*72];
  int tid = threadIdx.x;
  int bid = blockIdx.x;
  int g = bid>>6, t = bid&63;
  int m0 = (g*8 + (t&7))*128, n0 = (t>>3)*128;
  int w = tid>>6, l = tid&63;
  int wm = (w>>1)*64, wn = (w&1)*64;
  int lr = l&15, lq = l>>4;
  f32x4 acc[4][4] = {};
  for(int k0=0; k0<1024; k0+=64){
    __syncthreads();   // previous compute done reading LDS
    #pragma unroll
    for(int j=0;j<8;++j){
      int idx = tid + 256*j;
      int m = idx>>4, q = idx&15;
      float4 u = *(const float4*)(A + (size_t)(m0+m)*1024 + k0 + 4*q);
      f16x4 hv; hv[0]=(f16)u.x; hv[1]=(f16)u.y; hv[2]=(f16)u.z; hv[3]=(f16)u.w;
      *(f16x4*)&Al[m*72 + 4*q] = hv;
    }
    #pragma unroll
    for(int j=0;j<4;++j){
      int idx = tid + 256*j;
      int n = idx>>3, o8 = idx&7;
      f16x8 hv = *(const f16x8*)(BT + (size_t)(n0+n)*1024 + k0 + 8*o8);
      *(f16x8*)&Bl[n*72 + 8*o8] = hv;
    }
    __syncthreads();
    #pragma unroll
    for(int kb=0; kb<64; kb+=32){
      f16x8 a[4], b[4];
      #pragma unroll
      for(int i=0;i<4;++i){
        a[i] = *(const f16x8*)&Al[(wm + i*16 + lr)*72 + kb + 8*lq];
        b[i] = *(const f16x8*)&Bl[(wn + i*16 + lr)*72 + kb + 8*lq];
      }
      #pragma unroll
      for(int mi=0;mi<4;++mi)
        #pragma unroll
        for(int ni=0;ni<4;++ni)
          acc[mi][ni] = __builtin_amdgcn_mfma_f32_16x16x32_f16(a[mi], b[ni], acc[mi][ni], 0,0,0);
    }
  }
  #pragma unroll
  for(int mi=0;mi<4;++mi){
    #pragma unroll
    for(int r=0;r<4;++r){
      int m = m0 + wm + mi*16 + lq*4 + r;
      #pragma unroll
      for(int ni=0;ni<4;++ni){
        int n = n0 + wn + ni*16 + lr;
        size_t o = (size_t)m*1024 + n;
        float v = acc[mi][ni][r];
        if(addres) v += resid[o];
        C[o] = v;
      }
    }
  }
}

// ---------------------------------------------------------------------------
// K3: per-chunk: cum, KK, forward substitution -> v_corr (in-place in vbuf),
//     wk_cd -> wkop. Also zeroes this chunk's psum/cnt team-sync slot.
// ---------------------------------------------------------------------------
__global__ __launch_bounds__(256) void k_chunk(const float* __restrict__ x,
    const float* __restrict__ invn, const float* __restrict__ beta_g,
    const float* __restrict__ dec_g, float* __restrict__ cum_g,
    float* __restrict__ vbuf, float* __restrict__ wkop,
    float* __restrict__ psum, int* __restrict__ cnt){
  int bid = blockIdx.x;                  // b*H*N + h*N + n  == bh*64 + n
  int n = bid & 63; int h = (bid>>6) & 15; int b = bid>>10;
  int t0 = n*C_;
  __shared__ float sm[12608];
  float* WK = sm;            // 64*65 (padded), aliased by XV later
  float* KK = sm+4160;       // 64*64
  float* XW = sm+8256;       // 64*64
  float* BS = sm+12352;      // 64
  float* CU = sm+12416;      // 64
  float* DE = sm+12480;      // 64
  float* GS = sm+12544;      // 64
  float* XV = WK;            // 4096 over WK region (stride 64)
  int tid = threadIdx.x, w = tid>>6, l = tid&63;
  if(tid==0){ psum[bid]=0.f; cnt[bid]=0; }   // reset team-sync slot for k_scan
  // A: stage shifted normalized keys + beta + decay
  #pragma unroll
  for(int it=0; it<16; ++it){
    int idx = tid + 256*it; int c = idx>>6, dd = idx&63;
    int tw = t0+c-1;
    float wv = 0.f;
    if(tw>=0){
      size_t rr = (size_t)(b*T_+tw);
      wv = x[rr*D_ + h*64 + dd] * invn[rr*H_ + h];
    }
    WK[c*65+dd] = wv;
  }
  if(tid<64){
    size_t rr = (size_t)(b*T_+t0+tid);
    BS[tid] = beta_g[rr*H_+h];
    GS[tid] = dec_g[rr*H_+h];
  }
  __syncthreads();
  // B: inclusive cumsum of decay (wave 0)
  if(w==0){
    float xg = GS[l];
    #pragma unroll
    for(int off=1; off<64; off<<=1){
      float y = __shfl_up(xg, off);
      if(l>=off) xg += y;
    }
    CU[l]=xg; DE[l]=expf(xg);
    cum_g[(size_t)bid*64 + l] = xg;
  }
  __syncthreads();
  // C: KK[i][j] = beta_i * (wk_i . wk_j) * L[i][j], strict lower
  float wkj[64];
  #pragma unroll
  for(int dd=0; dd<64; ++dd) wkj[dd] = WK[l*65+dd];
  #pragma unroll 1
  for(int it=0; it<16; ++it){
    int i = w + 4*it;
    float aw=0.f;
    #pragma unroll
    for(int dd=0; dd<64; ++dd) aw += WK[i*65+dd]*wkj[dd];
    KK[i*64+l] = (l<i) ? (BS[i]*aw*expf(CU[i]-CU[l])) : 0.f;
  }
  __syncthreads();
  // D: capture rhs into regs, then write XV (over WK), XW
  float rv[16], rw[16];
  #pragma unroll
  for(int it=0; it<16; ++it){
    int i = w + 4*it;
    rw[it] = WK[i*65+l]*BS[i]*DE[i];
    rv[it] = vbuf[(size_t)(b*T_+t0+i)*D_ + h*64 + l]*BS[i];
  }
  __syncthreads();
  #pragma unroll
  for(int it=0; it<16; ++it){
    int i = w + 4*it;
    XV[i*64+l] = rv[it];
    XW[i*64+l] = rw[it];
  }
  __syncthreads();
  // E: forward substitution (I + strict_lower(KK)) X = rhs (waves 0,1)
  if(w<2){
    float* Xc = (w==0) ? XV : XW;
    for(int i=1;i<64;++i){
      float acc = Xc[i*64+l];
      for(int k=0;k<i;++k) acc -= KK[i*64+k]*Xc[k*64+l];
      Xc[i*64+l] = acc;
    }
  }
  __syncthreads();
  // F: write v_corr (in place), wk_cd
  #pragma unroll
  for(int it=0; it<16; ++it){
    int i = w + 4*it;
    vbuf[(size_t)(b*T_+t0+i)*D_ + h*64 + l] = XV[i*64+l];
    wkop[(size_t)bid*4096 + i*64 + l]       = XW[i*64+l];
  }
}

// ---------------------------------------------------------------------------
// K4 v4b: column-split team scan (verified at 477 us, round 4/5).
//   256 blocks = 64 (b,h) chains x 4 col-groups of 16 columns. Cross-column
//   coupling (Frobenius clip) via device-scope atomics per (bh,chunk);
//   S kept UNSCALED in LDS, scale applied lazily next chunk; bounded spin.
// ---------------------------------------------------------------------------
__global__ __launch_bounds__(1024, 4) void k_scan(const float* __restrict__ x,
    const float* __restrict__ invn_g, const float* __restrict__ cum_g,
    float* __restrict__ vbuf, float* __restrict__ wkop,
    float* __restrict__ psum, int* __restrict__ cnt){
  int bh = blockIdx.x & 63, cg = blockIdx.x >> 6;
  int b = bh>>4, h = bh&15, col0 = cg*16;
  __shared__ float sm[15448];
  float* WCD = sm;           // [64][68] wkcd rows
  float* RK  = sm+4352;      // [64][68] rk rows (scaled by invn)
  float* WKT = sm+8704;      // [64][68] WKT[d][c] = wk[c][d] (col 0 = PREV)
  float* VNS = sm+13056;     // [16][68] VNS[col][c] = v_new*DW, transposed
  float* ST  = sm+14144;     // [16][68] ST[col][d] = S (UNSCALED U), transposed
  float* DW  = sm+15232;     // 64: exp(last-cum)
  float* DEc = sm+15296;     // 64: exp(cum)
  float* PREV= sm+15360;     // 64: prev chunk's last rk row
  float* P   = sm+15424;     // 16
  float* NRM = sm+15440;     // 1
  int tid = threadIdx.x, w = tid>>6, l = tid&63;
  int c = tid>>4, q4 = tid&15;     // row / float4-slot (stage)
  int col = tid&15;                // local column (compute)

  for(int i=tid;i<1088;i+=1024) ST[i]=0.f;
  if(tid<64) PREV[tid]=0.f;

  // prologue prefetch chunk 0
  float4 pW, pR; float pIv, pV, pC=0.f, pLast=0.f;
  {
    size_t base0 = (size_t)bh*N_*4096;
    pW = *(const float4*)(wkop + base0 + (size_t)tid*4);
    pR = *(const float4*)(x + (size_t)(b*T_+c)*D_ + h*64 + 4*q4);
    pIv = invn_g[(size_t)(b*T_+c)*H_ + h];
    pV  = vbuf[(size_t)(b*T_+c)*D_ + h*64 + col0+col];
    if(tid<64){
      pC    = cum_g[(size_t)bh*N_*64 + tid];
      pLast = cum_g[(size_t)bh*N_*64 + 63];
    }
  }
  __syncthreads();

  float scale = 1.f;
  for(int n=0;n<N_;++n){
    int t0 = n*C_;
    size_t base = ((size_t)bh*N_+n)*4096;
    // ---- stage ----
    *(float4*)&WCD[c*68+4*q4] = pW;
    float4 rv4;
    rv4.x=pR.x*pIv; rv4.y=pR.y*pIv; rv4.z=pR.z*pIv; rv4.w=pR.w*pIv;
    *(float4*)&RK[c*68+4*q4] = rv4;
    if(c<63){
      WKT[(4*q4+0)*68 + c+1]=rv4.x;
      WKT[(4*q4+1)*68 + c+1]=rv4.y;
      WKT[(4*q4+2)*68 + c+1]=rv4.z;
      WKT[(4*q4+3)*68 + c+1]=rv4.w;
    }
    if(tid<64){
      WKT[tid*68+0] = PREV[tid];
      DW[tid]  = expf(pLast-pC);
      DEc[tid] = expf(pC);
    }
    // ---- bounded spin for previous chunk's team norm ----
    if(n>0 && tid==0){
      int slot = bh*N_ + n-1;
      int guard = 0;
      while(__hip_atomic_load(&cnt[slot], __ATOMIC_ACQUIRE, __HIP_MEMORY_SCOPE_AGENT) < 4
            && guard < (1<<20)){
        __builtin_amdgcn_s_sleep(8);
        ++guard;
      }
      NRM[0] = __hip_atomic_load(&psum[slot], __ATOMIC_RELAXED, __HIP_MEMORY_SCOPE_AGENT);
    }
    __syncthreads();   // B1
    if(n>0){
      float nr = sqrtf(NRM[0]);
      scale = fminf(nr,100.f)/fmaxf(nr,1e-6f);
    }
    float vcur = pV;
    // ---- prefetch chunk n+1 (drained by B3 before the release-add) ----
    if(n+1<N_){
      int t1 = t0 + C_;
      size_t base1 = base + 4096;
      pW = *(const float4*)(wkop + base1 + (size_t)tid*4);
      pR = *(const float4*)(x + (size_t)(b*T_+t1+c)*D_ + h*64 + 4*q4);
      pIv = invn_g[(size_t)(b*T_+t1+c)*H_ + h];
      pV  = vbuf[(size_t)(b*T_+t1+c)*D_ + h*64 + col0+col];
      if(tid<64){
        pC    = cum_g[((size_t)bh*N_+n+1)*64 + tid];
        pLast = cum_g[((size_t)bh*N_+n+1)*64 + 63];
      }
    }
    // ---- gemv: thread (c,col). S used = scale * ST (lazy) ----
    float da=0.f, dro=0.f;
    #pragma unroll
    for(int q=0;q<16;++q){
      float4 wv = *(const float4*)&WCD[c*68+4*q];
      float4 rr = *(const float4*)&RK [c*68+4*q];
      float4 sv = *(const float4*)&ST [col*68+4*q];
      da  += wv.x*sv.x+wv.y*sv.y+wv.z*sv.z+wv.w*sv.w;
      dro += rr.x*sv.x+rr.y*sv.y+rr.z*sv.z+rr.w*sv.w;
    }
    float vn = vcur - scale*da;
    vbuf[(size_t)(b*T_+t0+c)*D_ + h*64 + col0+col] = vn;
    wkop[base + c*64 + col0+col] = DEc[c]*scale*dro;
    VNS[col*68+c] = vn*DW[c];
    __syncthreads();   // B2
    if(tid<64) PREV[tid] = RK[63*68+tid];
    // ---- S update ----
    float sold = ST[col*68+c];
    float sn = DEc[63]*scale*sold;
    #pragma unroll
    for(int q=0;q<16;++q){
      float4 wt = *(const float4*)&WKT[c*68+4*q];
      float4 vt = *(const float4*)&VNS[col*68+4*q];
      sn += wt.x*vt.x+wt.y*vt.y+wt.z*vt.z+wt.w*vt.w;
    }
    float p = sn*sn;
    p = wave_sum(p);
    if(l==0) P[w]=p;
    __syncthreads();   // B3 (drains vmcnt: prefetches landed before release)
    if(tid==0 && n+1<N_){
      float pl=0.f;
      #pragma unroll
      for(int i=0;i<16;++i) pl += P[i];
      int slot = bh*N_ + n;
      __hip_atomic_fetch_add(&psum[slot], pl, __ATOMIC_RELAXED, __HIP_MEMORY_SCOPE_AGENT);
      __hip_atomic_fetch_add(&cnt[slot], 1, __ATOMIC_RELEASE, __HIP_MEMORY_SCOPE_AGENT);
    }
    ST[col*68+c] = sn;   // unscaled; next gemv applies scale
  }
}

// ---------------------------------------------------------------------------
// K5: o = gate*(opart + intra @ v_new); intra recomputed from rk/wk; o in-place
// ---------------------------------------------------------------------------
__global__ __launch_bounds__(256) void k_o(const float* __restrict__ x,
    const float* __restrict__ invn, const float* __restrict__ cum_g,
    const float* __restrict__ wkop, const float* __restrict__ gate_g,
    float* __restrict__ vbuf){
  int bid = blockIdx.x; int n = bid&63, h=(bid>>6)&15, b=bid>>10;
  int t0 = n*C_;
  __shared__ float sm[8256];
  float* RK = sm;        // 64x64 rk chunk, later INT (intra)
  float* VN = sm+4096;   // 64x64 v_new chunk
  float* CU = sm+8192;   // 64
  float* INT = RK;
  int tid=threadIdx.x, w=tid>>6, l=tid&63;
  if(tid<64) CU[tid] = cum_g[(size_t)bid*64 + tid];
  #pragma unroll 1
  for(int it=0;it<16;++it){
    int idx = tid+256*it; int c=idx>>6, dd=idx&63;
    size_t rr = (size_t)(b*T_+t0+c);
    RK[c*64+dd] = x[rr*D_ + h*64 + dd] * invn[rr*H_ + h];
    VN[idx]     = vbuf[rr*D_ + h*64 + dd];
  }
  __syncthreads();
  float wkj[64];
  {
    int tw = t0+l-1;
    if(tw>=0){
      size_t r2 = (size_t)(b*T_+tw);
      float iv = invn[r2*H_ + h];
      #pragma unroll
      for(int d4=0; d4<16; ++d4){
        float4 u = *(const float4*)(x + r2*D_ + h*64 + 4*d4);
        wkj[4*d4+0]=u.x*iv; wkj[4*d4+1]=u.y*iv;
        wkj[4*d4+2]=u.z*iv; wkj[4*d4+3]=u.w*iv;
      }
    } else {
      #pragma unroll
      for(int dd=0;dd<64;++dd) wkj[dd]=0.f;
    }
  }
  #pragma unroll 1
  for(int it=0;it<16;++it){
    int i = w + 4*it;
    float ar = 0.f;
    #pragma unroll
    for(int d4=0; d4<16; ++d4){
      float4 r4 = *(const float4*)&RK[i*64 + 4*d4];
      ar += r4.x*wkj[4*d4] + r4.y*wkj[4*d4+1] + r4.z*wkj[4*d4+2] + r4.w*wkj[4*d4+3];
    }
    float val = (l<=i) ? (ar*expf(CU[i]-CU[l])) : 0.f;
    INT[i*64+l] = val;
  }
  __syncthreads();
  float vn_col[64];
  #pragma unroll
  for(int k=0;k<64;++k) vn_col[k] = VN[k*64+l];
  #pragma unroll 1
  for(int it=0;it<16;++it){
    int c = w+4*it;
    float acc = 0.f;
    #pragma unroll
    for(int d4=0; d4<16; ++d4){
      float4 i4 = *(const float4*)&INT[c*64 + 4*d4];
      acc += i4.x*vn_col[4*d4] + i4.y*vn_col[4*d4+1] + i4.z*vn_col[4*d4+2] + i4.w*vn_col[4*d4+3];
    }
    size_t rr = (size_t)(b*T_+t0+c);
    float g  = gate_g[rr*H_ + h];
    float op = wkop[(size_t)bid*4096 + c*64 + l];
    vbuf[rr*D_ + h*64 + l] = (op + acc)*g;
  }
}

// ---------------------------------------------------------------------------
extern "C" void kernel_launch(void* const* d_in, const int* in_sizes, int n_in,
                              void* d_out, int out_size, void* d_ws, size_t ws_size,
                              hipStream_t stream) {
  const float* x       = (const float*)d_in[0];
  const float* w_write = (const float*)d_in[1];
  const float* w_gate  = (const float*)d_in[2];
  const float* w_out   = (const float*)d_in[3];
  const float* w_beta  = (const float*)d_in[4];
  const float* w_alpha = (const float*)d_in[5];
  const float* dt_bias = (const float*)d_in[6];
  const float* A_log   = (const float*)d_in[7];
  float* outp = (float*)d_out;

  const size_t big   = (size_t)BT_*D_;   // 16,777,216 floats
  const size_t small = (size_t)BT_*H_;   //    262,144 floats
  const size_t nslot = (size_t)B_*H_*N_; //       4096 team-sync slots
  const size_t wsz   = (size_t)D_*D_;    //  1,048,576 halves per weight
  const size_t need  = (2*big + 5*small + 2*nslot)*sizeof(float) + 2*wsz*sizeof(f16);
  if(ws_size < need) return;   // diagnostic: wrong-answer instead of fault

  float* ws   = (float*)d_ws;
  float* vbuf = ws;              // v -> v_corr -> v_new -> o
  float* wkop = vbuf + big;      // wk_cd -> opart
  float* invn = wkop + big;
  float* gate = invn + small;
  float* beta = gate + small;
  float* dec  = beta + small;
  float* cum  = dec  + small;
  float* psum = cum  + small;
  int*   cnt  = (int*)(psum + nslot);
  f16*   wtw  = (f16*)(cnt + nslot);     // w_write^T in f16 [n][k]
  f16*   wto  = wtw + wsz;               // w_out^T   in f16 [n][k]

  k_tr<<<dim3(16,16,2), dim3(256), 0, stream>>>(w_write, w_out, wtw, wto);
  k_small<<<dim3(BT_/KSR), dim3(256), 0, stream>>>(x, w_gate, w_beta, w_alpha,
      dt_bias, A_log, invn, gate, beta, dec);
  k_gemm16<<<dim3(1024), dim3(256), 0, stream>>>(x, wtw,
      (const float*)0, vbuf, 0);
  k_chunk<<<dim3(B_*H_*N_), dim3(256), 0, stream>>>(x, invn, beta, dec,
      cum, vbuf, wkop, psum, cnt);
  k_scan<<<dim3(4*B_*H_), dim3(1024), 0, stream>>>(x, invn, cum, vbuf, wkop,
      psum, cnt);
  k_o<<<dim3(B_*H_*N_), dim3(256), 0, stream>>>(x, invn, cum, wkop, gate, vbuf);
  k_gemm16<<<dim3(1024), dim3(256), 0, stream>>>(vbuf, wto, x,
      outp, 1);
}